// Round 7
// baseline (1866.199 us; speedup 1.0000x reference)
//
#include <hip/hip_runtime.h>
#include <stdint.h>

typedef _Float16 f16;
typedef _Float16 f16x8 __attribute__((ext_vector_type(8)));
typedef float f32x4 __attribute__((ext_vector_type(4)));

#define TT 256
#define BB 256
#define II 128
#define HH 512
#define G4 2048
#define NGRP 8
#define NSLC 16
static constexpr size_t BH = (size_t)BB * HH;

// ---------------- coherence helpers (sc1/agent ONLY — proven protocol) ----------------
__device__ __forceinline__ uint64_t ld_agent_u64(const uint64_t* p) {
  return __hip_atomic_load(p, __ATOMIC_RELAXED, __HIP_MEMORY_SCOPE_AGENT);
}
__device__ __forceinline__ void st_agent_u64(uint64_t* p, uint64_t v) {
  __hip_atomic_store(p, v, __ATOMIC_RELAXED, __HIP_MEMORY_SCOPE_AGENT);
}
__device__ __forceinline__ void st_agent_u16(uint16_t* p, uint16_t v) {
  __hip_atomic_store(p, v, __ATOMIC_RELAXED, __HIP_MEMORY_SCOPE_AGENT);
}
// 8x dwordx4 sc1 loads: 4 granule-groups of h1-row-part + 4 of h2-row-part.
// Ends with vmcnt(4) so the h1 quads are ready; caller drains vmcnt(0) before
// touching v[4..7]. All outputs early-clobber.
__device__ __forceinline__ void ld8_sc1(const void* b1, const void* b2, uint4 v[8]) {
  asm volatile(
      "global_load_dwordx4 %0, %8, off sc1\n\t"
      "global_load_dwordx4 %1, %8, off offset:256 sc1\n\t"
      "global_load_dwordx4 %2, %8, off offset:512 sc1\n\t"
      "global_load_dwordx4 %3, %8, off offset:768 sc1\n\t"
      "global_load_dwordx4 %4, %9, off sc1\n\t"
      "global_load_dwordx4 %5, %9, off offset:256 sc1\n\t"
      "global_load_dwordx4 %6, %9, off offset:512 sc1\n\t"
      "global_load_dwordx4 %7, %9, off offset:768 sc1\n\t"
      "s_waitcnt vmcnt(4)"
      : "=&v"(v[0]), "=&v"(v[1]), "=&v"(v[2]), "=&v"(v[3]),
        "=&v"(v[4]), "=&v"(v[5]), "=&v"(v[6]), "=&v"(v[7])
      : "v"(b1), "v"(b2)
      : "memory");
}

__device__ __forceinline__ float fsig(float x) {
  x = fminf(fmaxf(x, -30.f), 30.f);
  float e = __builtin_amdgcn_exp2f(-1.44269504f * x);
  return __builtin_amdgcn_rcpf(1.f + e);
}
__device__ __forceinline__ float ftanh(float x) {
  x = fminf(fmaxf(x, -15.f), 15.f);
  float e = __builtin_amdgcn_exp2f(-2.88539008f * x);  // exp(-2x)
  return (1.f - e) * __builtin_amdgcn_rcpf(1.f + e);
}

// swizzled LDS fragment reads (granule = 16B, XOR with row&7)
__device__ __forceinline__ f16x8 ldfragh(const f16* S, int row, int gi) {
  return *(const f16x8*)(S + row * 512 + ((gi ^ (row & 7)) * 8));
}
__device__ __forceinline__ f16x8 ldfragx(const f16* S, int row, int gi) {
  return *(const f16x8*)(S + row * 128 + ((gi ^ (row & 7)) * 8));
}

__global__ void k_diag(float* out, float val) { out[0] = val; }

// ---------------- x transpose/convert: [B][T][I] f32 -> [T][B][I] f16 ----------------
__global__ __launch_bounds__(256) void k_conv_x(const float* __restrict__ x,
                                                f16* __restrict__ xt) {
  int idx = blockIdx.x * 256 + threadIdx.x;  // unit = 8 floats
  int row = idx >> 4;                        // row = t*B + b
  int ii = (idx & 15) * 8;
  int t = row >> 8, b = row & 255;
  const float4* xs = (const float4*)(x + ((size_t)b * TT + t) * II + ii);
  float4 v0 = xs[0];
  float4 v1 = xs[1];
  f16x8 h;
  h[0] = (f16)v0.x; h[1] = (f16)v0.y; h[2] = (f16)v0.z; h[3] = (f16)v0.w;
  h[4] = (f16)v1.x; h[5] = (f16)v1.y; h[6] = (f16)v1.z; h[7] = (f16)v1.w;
  *(f16x8*)(xt + (size_t)row * II + ii) = h;
}

// ---------------- convert weights to f16, sum biases ----------------
__global__ __launch_bounds__(256) void k_conv_w(
    const float* __restrict__ wih0, const float* __restrict__ whh0,
    const float* __restrict__ wih1, const float* __restrict__ whh1,
    const float* __restrict__ bih0, const float* __restrict__ bhh0,
    const float* __restrict__ bih1, const float* __restrict__ bhh1,
    f16* owih0, f16* owhh0, f16* owih1, f16* owhh1, float* ob0, float* ob1) {
  int i = blockIdx.x * 256 + threadIdx.x;
  if (i < G4 * II) owih0[i] = (f16)wih0[i];
  if (i < G4 * HH) {
    owhh0[i] = (f16)whh0[i];
    owih1[i] = (f16)wih1[i];
    owhh1[i] = (f16)whh1[i];
  }
  if (i < G4) {
    ob0[i] = bih0[i] + bhh0[i];
    ob1[i] = bih1[i] + bhh1[i];
  }
}

// ---------------- fused 2-layer wavefront LSTM ----------------
// 128 blocks x 512 threads = 8 batch-groups (grp=bx&7, 32 rows) x 16
// col-slices (slice=bx>>3, 32 h-cols / 128 gate-cols). Tick u: L0 step u
// (u<T), L1 step u-1 (u>=1). Each wave owns 16 gate-cols (one gate x half
// the cols) with 52 f16x8 weights in VGPRs — identical per-wave shape to the
// proven R5 kernel; one h1+h2 staging now feeds 2x the compute (8 MB/tick
// total vs 16). Handshake: sc1 flag line per (grp,tick), 16 u16 slots.
__global__ __launch_bounds__(512, 2) void k_fused(
    const f16* __restrict__ xt,
    const f16* __restrict__ Wih0, const f16* __restrict__ Whh0,
    const f16* __restrict__ Wih1, const f16* __restrict__ Whh1,
    const float* __restrict__ b0, const float* __restrict__ b1,
    f16* __restrict__ h1r, f16* __restrict__ h2r, uint16_t* __restrict__ flags) {
  __shared__ __align__(16) f16 h1s[32 * 512];    // 32KB, swizzled
  __shared__ __align__(16) f16 h2s[32 * 512];    // 32KB, swizzled
  __shared__ __align__(16) f16 xs[32 * 128];     // 8KB, swizzled
  __shared__ __align__(16) float gs[2][128][36]; // 36KB gate preacts
  __shared__ float bl[2][4][32];                 // 1KB bias

  int tid = threadIdx.x;
  int l64 = tid & 63;
  int wid = tid >> 6;        // 0..7
  int g = wid >> 1;          // gate chunk (i,f,g,o)
  int ch = wid & 1;          // col half
  int lm = l64 & 15, ls = l64 >> 4;
  int bx = blockIdx.x;
  int grp = bx & 7;
  int slice = bx >> 3;       // 0..15
  int col0 = slice * 32;
  int row0 = grp * 32;

  // ---- bias -> LDS ----
  if (tid < 256) {
    int el_ = tid >> 7, gt = (tid >> 5) & 3, cl = tid & 31;
    const float* bsrc = el_ ? b1 : b0;
    bl[el_][gt][cl] = bsrc[gt * HH + col0 + cl];
  }

  // ---- preload weight fragments: 52 f16x8 = 208 VGPRs ----
  int wrow = g * 512 + col0 + ch * 16 + lm;  // weight row (gate-col)
  f16x8 wih0f[4], whh0f[16], wih1f[16], whh1f[16];
#pragma unroll
  for (int kk = 0; kk < 4; ++kk)
    wih0f[kk] = *(const f16x8*)(Wih0 + (size_t)wrow * II + kk * 32 + ls * 8);
#pragma unroll
  for (int kk = 0; kk < 16; ++kk) {
    whh0f[kk] = *(const f16x8*)(Whh0 + (size_t)wrow * HH + kk * 32 + ls * 8);
    wih1f[kk] = *(const f16x8*)(Wih1 + (size_t)wrow * HH + kk * 32 + ls * 8);
    whh1f[kk] = *(const f16x8*)(Whh1 + (size_t)wrow * HH + kk * 32 + ls * 8);
  }

  // ---- elementwise role: 4 cells/thread ----
  int el = tid >> 8;         // layer
  int er = (tid >> 3) & 31;  // local batch row
  int eq = tid & 7;          // col quad (cols eq*4..+3 of 32)
  float cst[4] = {0.f, 0.f, 0.f, 0.f};
  f16* ering = el ? h2r : h1r;

  // staging role: row sr = tid>>4 (0..31), granule gq = tid&15 (16B units)
  int sr = tid >> 4;
  int gq = tid & 15;
  const uint64_t kTarget = 0x0001000100010001ULL;
  __syncthreads();

#pragma unroll 1
  for (int u = 0; u <= TT; ++u) {
    // prefetch x_u into regs (plain load; hides under poll)
    uint4 xv;
    if (u < TT)
      xv = ((const uint4*)(xt + ((size_t)u * BB + row0 + sr) * II))[gq];
    if (u > 0) {
      // poll the (grp, u-1) flag line: 16 u16 slots == 1 (2 u64 words)
      const uint64_t* fl =
          (const uint64_t*)(flags + ((size_t)grp * (TT + 1) + (u - 1)) * 32);
      int guard = 0;
      for (;;) {
        uint64_t v = ld_agent_u64(fl + (l64 & 1));
        if (__all(v == kTarget)) break;
        if (++guard > 500000) break;  // deadlock safety net
        __builtin_amdgcn_s_sleep(1);
      }
      asm volatile("" ::: "memory");  // no hoisting data loads above poll
      // ---- stage h1_{u-1} (slot (u-1)&1) and h2_{u-2} (slot u&1) ----
      const f16* base1 =
          h1r + (size_t)((u - 1) & 1) * BH + (size_t)(row0 + sr) * HH + gq * 8;
      const f16* base2 =
          h2r + (size_t)(u & 1) * BH + (size_t)(row0 + sr) * HH + gq * 8;
      uint4 v[8];
      ld8_sc1(base1, base2, v);  // ends with vmcnt(4): h1 quads ready
      uint4* d1 = (uint4*)h1s;
      uint4* d2 = (uint4*)h2s;
#pragma unroll
      for (int q = 0; q < 4; ++q) {
        int gi = gq + q * 16;
        d1[sr * 64 + (gi ^ (sr & 7))] = v[q];
      }
      asm volatile("s_waitcnt vmcnt(0)" ::: "memory");  // h2 quads ready
#pragma unroll
      for (int q = 0; q < 4; ++q) {
        int gi = gq + q * 16;
        d2[sr * 64 + (gi ^ (sr & 7))] = v[4 + q];
      }
    }
    if (u < TT) {  // x -> swizzled LDS
      ((uint4*)xs)[sr * 16 + (gq ^ (sr & 7))] = xv;
    }
    __syncthreads();

    // ---- MFMA: wave (g,ch) -> 16 gate-cols, 32 rows, both layers ----
    f32x4 a0f0 = {0.f, 0.f, 0.f, 0.f}, a0f1 = {0.f, 0.f, 0.f, 0.f};
    f32x4 a1f0 = {0.f, 0.f, 0.f, 0.f}, a1f1 = {0.f, 0.f, 0.f, 0.f};
    if (u < TT) {  // L0 x-projection, K=128
#pragma unroll
      for (int kk = 0; kk < 4; ++kk) {
        f16x8 xA = ldfragx(xs, lm, kk * 4 + ls);
        f16x8 xB = ldfragx(xs, 16 + lm, kk * 4 + ls);
        a0f0 = __builtin_amdgcn_mfma_f32_16x16x32_f16(xA, wih0f[kk], a0f0, 0, 0, 0);
        a0f1 = __builtin_amdgcn_mfma_f32_16x16x32_f16(xB, wih0f[kk], a0f1, 0, 0, 0);
      }
    }
    if (u > 0) {  // h1_{u-1} feeds L0 recurrence AND L1 input projection
#pragma unroll
      for (int kk = 0; kk < 16; ++kk) {
        f16x8 hA = ldfragh(h1s, lm, kk * 4 + ls);
        f16x8 hB = ldfragh(h1s, 16 + lm, kk * 4 + ls);
        if (u < TT) {
          a0f0 = __builtin_amdgcn_mfma_f32_16x16x32_f16(hA, whh0f[kk], a0f0, 0, 0, 0);
          a0f1 = __builtin_amdgcn_mfma_f32_16x16x32_f16(hB, whh0f[kk], a0f1, 0, 0, 0);
        }
        a1f0 = __builtin_amdgcn_mfma_f32_16x16x32_f16(hA, wih1f[kk], a1f0, 0, 0, 0);
        a1f1 = __builtin_amdgcn_mfma_f32_16x16x32_f16(hB, wih1f[kk], a1f1, 0, 0, 0);
      }
      if (u >= 2) {  // L1 recurrence over h2_{u-2}
#pragma unroll
        for (int kk = 0; kk < 16; ++kk) {
          f16x8 hA = ldfragh(h2s, lm, kk * 4 + ls);
          f16x8 hB = ldfragh(h2s, 16 + lm, kk * 4 + ls);
          a1f0 = __builtin_amdgcn_mfma_f32_16x16x32_f16(hA, whh1f[kk], a1f0, 0, 0, 0);
          a1f1 = __builtin_amdgcn_mfma_f32_16x16x32_f16(hB, whh1f[kk], a1f1, 0, 0, 0);
        }
      }
    }
    // acc -> gs[layer][gl][row]; gl = g*32 + ch*16 + lm
    int gl = g * 32 + ch * 16 + lm;
    *(f32x4*)&gs[0][gl][ls * 4] = a0f0;
    *(f32x4*)&gs[0][gl][16 + ls * 4] = a0f1;
    *(f32x4*)&gs[1][gl][ls * 4] = a1f0;
    *(f32x4*)&gs[1][gl][16 + ls * 4] = a1f1;
    __syncthreads();

    // ---- elementwise LSTM cell: layer el, row er, cols eq*4..+3 ----
    bool act = el ? (u >= 1) : (u < TT);
    if (act) {
      int t_l = el ? (u - 1) : u;
      int slot = t_l & 1;
      union { uint64_t v; unsigned short us[4]; } pk;
#pragma unroll
      for (int j = 0; j < 4; ++j) {
        int cl = eq * 4 + j;
        float pi = gs[el][0 * 32 + cl][er] + bl[el][0][cl];
        float pf = gs[el][1 * 32 + cl][er] + bl[el][1][cl];
        float pg = gs[el][2 * 32 + cl][er] + bl[el][2][cl];
        float po = gs[el][3 * 32 + cl][er] + bl[el][3][cl];
        float ig = fsig(pi), fg = fsig(pf), gg = ftanh(pg), og = fsig(po);
        cst[j] = fg * cst[j] + ig * gg;
        pk.us[j] = __builtin_bit_cast(unsigned short, (f16)(og * ftanh(cst[j])));
      }
      uint64_t* dst = (uint64_t*)(ering + (size_t)slot * BH +
                                  (size_t)(row0 + er) * HH + col0 + eq * 4);
      st_agent_u64(dst, pk.v);
    }
    asm volatile("s_waitcnt vmcnt(0)" ::: "memory");  // h stores at MALL
    __syncthreads();                                  // all waves drained
    if (u < TT && tid == 0)  // parallel flag store: no RMW
      st_agent_u16(flags + ((size_t)grp * (TT + 1) + u) * 32 + slice, 1u);
  }
}

// ---------------- FC head: out[b] = h2_last[b][:] . fcw + fcb ----------------
__global__ __launch_bounds__(64) void k_fc(const f16* __restrict__ h2,
                                           const float* __restrict__ fcw,
                                           const float* __restrict__ fcb,
                                           float* __restrict__ out) {
  int b = blockIdx.x;
  int l = threadIdx.x;
  f16x8 hv = *(const f16x8*)(h2 + (size_t)b * HH + l * 8);
  float4 w0 = ((const float4*)fcw)[l * 2];
  float4 w1 = ((const float4*)fcw)[l * 2 + 1];
  float s = (float)hv[0] * w0.x + (float)hv[1] * w0.y + (float)hv[2] * w0.z +
            (float)hv[3] * w0.w + (float)hv[4] * w1.x + (float)hv[5] * w1.y +
            (float)hv[6] * w1.z + (float)hv[7] * w1.w;
#pragma unroll
  for (int off = 32; off > 0; off >>= 1) s += __shfl_down(s, off);
  if (l == 0) out[b] = s + fcb[0];
}

// ---------------- launch ----------------
extern "C" void kernel_launch(void* const* d_in, const int* in_sizes, int n_in,
                              void* d_out, int out_size, void* d_ws, size_t ws_size,
                              hipStream_t stream) {
  (void)in_sizes; (void)n_in; (void)out_size;

  const float* x    = (const float*)d_in[0];
  const float* wih0 = (const float*)d_in[1];
  const float* whh0 = (const float*)d_in[2];
  const float* bih0 = (const float*)d_in[3];
  const float* bhh0 = (const float*)d_in[4];
  const float* wih1 = (const float*)d_in[5];
  const float* whh1 = (const float*)d_in[6];
  const float* bih1 = (const float*)d_in[7];
  const float* bhh1 = (const float*)d_in[8];
  const float* fcw  = (const float*)d_in[9];
  const float* fcb  = (const float*)d_in[10];

  const size_t SZ_XT   = (size_t)TT * BB * II * 2;              // 16.8 MB
  const size_t SZ_WIH0 = (size_t)G4 * II * 2;
  const size_t SZ_W    = (size_t)G4 * HH * 2;
  const size_t SZ_B    = (size_t)G4 * 4;
  const size_t SZ_RING = (size_t)2 * BH * 2;
  const size_t SZ_FLG  = (size_t)NGRP * (TT + 1) * 64;          // 64B line per (grp,tick)
  const size_t TOTAL =
      SZ_XT + SZ_WIH0 + 3 * SZ_W + 2 * SZ_B + 2 * SZ_RING + SZ_FLG;

  if (ws_size < TOTAL) {
    k_diag<<<1, 1, 0, stream>>>((float*)d_out, (float)(ws_size >> 20));
    return;
  }

  char* ws = (char*)d_ws;
  size_t off = 0;
  f16* xt    = (f16*)(ws + off); off += SZ_XT;
  f16* cwih0 = (f16*)(ws + off); off += SZ_WIH0;
  f16* cwhh0 = (f16*)(ws + off); off += SZ_W;
  f16* cwih1 = (f16*)(ws + off); off += SZ_W;
  f16* cwhh1 = (f16*)(ws + off); off += SZ_W;
  float* b0  = (float*)(ws + off); off += SZ_B;
  float* b1  = (float*)(ws + off); off += SZ_B;
  f16* h1r   = (f16*)(ws + off); off += SZ_RING;
  f16* h2r   = (f16*)(ws + off); off += SZ_RING;
  uint16_t* flags = (uint16_t*)(ws + off); off += SZ_FLG;

  hipMemsetAsync(flags, 0, SZ_FLG, stream);
  k_conv_w<<<4096, 256, 0, stream>>>(wih0, whh0, wih1, whh1, bih0, bhh0, bih1, bhh1,
                                     cwih0, cwhh0, cwih1, cwhh1, b0, b1);
  k_conv_x<<<4096, 256, 0, stream>>>(x, xt);
  k_fused<<<128, 512, 0, stream>>>(xt, cwih0, cwhh0, cwih1, cwhh1, b0, b1,
                                   h1r, h2r, flags);
  // h2_255 is in ring slot (255&1)==1
  k_fc<<<256, 64, 0, stream>>>(h2r + BH, fcw, fcb, (float*)d_out);
}

// Round 8
// 1862.502 us; speedup vs baseline: 1.0020x; 1.0020x over previous
//
#include <hip/hip_runtime.h>
#include <stdint.h>

typedef _Float16 f16;
typedef _Float16 f16x8 __attribute__((ext_vector_type(8)));
typedef float f32x4 __attribute__((ext_vector_type(4)));

#define TT 256
#define BB 256
#define II 128
#define HH 512
#define G4 2048
#define NGRP 8
#define NSLC 16
static constexpr size_t BH = (size_t)BB * HH;

// ---------------- coherence helpers (sc1/agent ONLY — proven protocol) ----------------
__device__ __forceinline__ uint64_t ld_agent_u64(const uint64_t* p) {
  return __hip_atomic_load(p, __ATOMIC_RELAXED, __HIP_MEMORY_SCOPE_AGENT);
}
__device__ __forceinline__ void st_agent_u64(uint64_t* p, uint64_t v) {
  __hip_atomic_store(p, v, __ATOMIC_RELAXED, __HIP_MEMORY_SCOPE_AGENT);
}
__device__ __forceinline__ void st_agent_u16(uint16_t* p, uint16_t v) {
  __hip_atomic_store(p, v, __ATOMIC_RELAXED, __HIP_MEMORY_SCOPE_AGENT);
}
// 8x dwordx4 sc1 loads: 4 granule-groups of h1-row-part + 4 of h2-row-part.
// Ends with vmcnt(4) so the h1 quads are ready; caller drains vmcnt(0) before
// touching v[4..7]. All outputs early-clobber.
__device__ __forceinline__ void ld8_sc1(const void* b1, const void* b2, uint4 v[8]) {
  asm volatile(
      "global_load_dwordx4 %0, %8, off sc1\n\t"
      "global_load_dwordx4 %1, %8, off offset:256 sc1\n\t"
      "global_load_dwordx4 %2, %8, off offset:512 sc1\n\t"
      "global_load_dwordx4 %3, %8, off offset:768 sc1\n\t"
      "global_load_dwordx4 %4, %9, off sc1\n\t"
      "global_load_dwordx4 %5, %9, off offset:256 sc1\n\t"
      "global_load_dwordx4 %6, %9, off offset:512 sc1\n\t"
      "global_load_dwordx4 %7, %9, off offset:768 sc1\n\t"
      "s_waitcnt vmcnt(4)"
      : "=&v"(v[0]), "=&v"(v[1]), "=&v"(v[2]), "=&v"(v[3]),
        "=&v"(v[4]), "=&v"(v[5]), "=&v"(v[6]), "=&v"(v[7])
      : "v"(b1), "v"(b2)
      : "memory");
}

__device__ __forceinline__ float fsig(float x) {
  x = fminf(fmaxf(x, -30.f), 30.f);
  float e = __builtin_amdgcn_exp2f(-1.44269504f * x);
  return __builtin_amdgcn_rcpf(1.f + e);
}
__device__ __forceinline__ float ftanh(float x) {
  x = fminf(fmaxf(x, -15.f), 15.f);
  float e = __builtin_amdgcn_exp2f(-2.88539008f * x);  // exp(-2x)
  return (1.f - e) * __builtin_amdgcn_rcpf(1.f + e);
}

// swizzled LDS fragment reads (granule = 16B, XOR with row&7)
__device__ __forceinline__ f16x8 ldfragh(const f16* S, int row, int gi) {
  return *(const f16x8*)(S + row * 512 + ((gi ^ (row & 7)) * 8));
}
__device__ __forceinline__ f16x8 ldfragx(const f16* S, int row, int gi) {
  return *(const f16x8*)(S + row * 128 + ((gi ^ (row & 7)) * 8));
}

__global__ void k_diag(float* out, float val) { out[0] = val; }

// ---------------- x transpose/convert: [B][T][I] f32 -> [T][B][I] f16 ----------------
__global__ __launch_bounds__(256) void k_conv_x(const float* __restrict__ x,
                                                f16* __restrict__ xt) {
  int idx = blockIdx.x * 256 + threadIdx.x;  // unit = 8 floats
  int row = idx >> 4;                        // row = t*B + b
  int ii = (idx & 15) * 8;
  int t = row >> 8, b = row & 255;
  const float4* xs = (const float4*)(x + ((size_t)b * TT + t) * II + ii);
  float4 v0 = xs[0];
  float4 v1 = xs[1];
  f16x8 h;
  h[0] = (f16)v0.x; h[1] = (f16)v0.y; h[2] = (f16)v0.z; h[3] = (f16)v0.w;
  h[4] = (f16)v1.x; h[5] = (f16)v1.y; h[6] = (f16)v1.z; h[7] = (f16)v1.w;
  *(f16x8*)(xt + (size_t)row * II + ii) = h;
}

// ---------------- convert weights to f16, sum biases ----------------
__global__ __launch_bounds__(256) void k_conv_w(
    const float* __restrict__ wih0, const float* __restrict__ whh0,
    const float* __restrict__ wih1, const float* __restrict__ whh1,
    const float* __restrict__ bih0, const float* __restrict__ bhh0,
    const float* __restrict__ bih1, const float* __restrict__ bhh1,
    f16* owih0, f16* owhh0, f16* owih1, f16* owhh1, float* ob0, float* ob1) {
  int i = blockIdx.x * 256 + threadIdx.x;
  if (i < G4 * II) owih0[i] = (f16)wih0[i];
  if (i < G4 * HH) {
    owhh0[i] = (f16)whh0[i];
    owih1[i] = (f16)wih1[i];
    owhh1[i] = (f16)whh1[i];
  }
  if (i < G4) {
    ob0[i] = bih0[i] + bhh0[i];
    ob1[i] = bih1[i] + bhh1[i];
  }
}

// ---------------- fused 2-layer wavefront LSTM ----------------
// 128 blocks x 512 threads = 8 batch-groups (grp=bx&7, 32 rows) x 16
// col-slices (slice=bx>>3, 32 h-cols / 128 gate-cols). Tick u: L0 step u
// (u<T), L1 step u-1 (u>=1). Each wave owns 16 gate-cols with 52 f16x8
// weights resident in the unified VGPR/AGPR file.
// NOTE: __launch_bounds__(512) WITHOUT a min-waves clamp — LDS (111KB)
// already pins 1 block/CU (2 waves/SIMD), which permits 256 arch VGPRs.
// R7's (512,2) capped VGPR at 128 and spilled the weights to scratch
// (~21 MB/tick reload traffic, +3 us/tick).
__global__ __launch_bounds__(512) void k_fused(
    const f16* __restrict__ xt,
    const f16* __restrict__ Wih0, const f16* __restrict__ Whh0,
    const f16* __restrict__ Wih1, const f16* __restrict__ Whh1,
    const float* __restrict__ b0, const float* __restrict__ b1,
    f16* __restrict__ h1r, f16* __restrict__ h2r, uint16_t* __restrict__ flags) {
  __shared__ __align__(16) f16 h1s[32 * 512];    // 32KB, swizzled
  __shared__ __align__(16) f16 h2s[32 * 512];    // 32KB, swizzled
  __shared__ __align__(16) f16 xs[32 * 128];     // 8KB, swizzled
  __shared__ __align__(16) float gs[2][128][36]; // 36KB gate preacts
  __shared__ float bl[2][4][32];                 // 1KB bias

  int tid = threadIdx.x;
  int l64 = tid & 63;
  int wid = tid >> 6;        // 0..7
  int g = wid >> 1;          // gate chunk (i,f,g,o)
  int ch = wid & 1;          // col half
  int lm = l64 & 15, ls = l64 >> 4;
  int bx = blockIdx.x;
  int grp = bx & 7;
  int slice = bx >> 3;       // 0..15
  int col0 = slice * 32;
  int row0 = grp * 32;

  // ---- bias -> LDS ----
  if (tid < 256) {
    int el_ = tid >> 7, gt = (tid >> 5) & 3, cl = tid & 31;
    const float* bsrc = el_ ? b1 : b0;
    bl[el_][gt][cl] = bsrc[gt * HH + col0 + cl];
  }

  // ---- preload weight fragments: 52 f16x8 = 208 regs (VGPR+AGPR) ----
  int wrow = g * 512 + col0 + ch * 16 + lm;  // weight row (gate-col)
  f16x8 wih0f[4], whh0f[16], wih1f[16], whh1f[16];
#pragma unroll
  for (int kk = 0; kk < 4; ++kk)
    wih0f[kk] = *(const f16x8*)(Wih0 + (size_t)wrow * II + kk * 32 + ls * 8);
#pragma unroll
  for (int kk = 0; kk < 16; ++kk) {
    whh0f[kk] = *(const f16x8*)(Whh0 + (size_t)wrow * HH + kk * 32 + ls * 8);
    wih1f[kk] = *(const f16x8*)(Wih1 + (size_t)wrow * HH + kk * 32 + ls * 8);
    whh1f[kk] = *(const f16x8*)(Whh1 + (size_t)wrow * HH + kk * 32 + ls * 8);
  }

  // ---- elementwise role: 4 cells/thread ----
  int el = tid >> 8;         // layer
  int er = (tid >> 3) & 31;  // local batch row
  int eq = tid & 7;          // col quad (cols eq*4..+3 of 32)
  float cst[4] = {0.f, 0.f, 0.f, 0.f};
  f16* ering = el ? h2r : h1r;

  // staging role: row sr = tid>>4 (0..31), granule gq = tid&15 (16B units)
  int sr = tid >> 4;
  int gq = tid & 15;
  const uint64_t kTarget = 0x0001000100010001ULL;
  __syncthreads();

#pragma unroll 1
  for (int u = 0; u <= TT; ++u) {
    // prefetch x_u into regs (plain load; hides under poll)
    uint4 xv;
    if (u < TT)
      xv = ((const uint4*)(xt + ((size_t)u * BB + row0 + sr) * II))[gq];
    if (u > 0) {
      // poll the (grp, u-1) flag line: 16 u16 slots == 1 (2 u64 words)
      const uint64_t* fl =
          (const uint64_t*)(flags + ((size_t)grp * (TT + 1) + (u - 1)) * 32);
      int guard = 0;
      for (;;) {
        uint64_t v = ld_agent_u64(fl + (l64 & 1));
        if (__all(v == kTarget)) break;
        if (++guard > 500000) break;  // deadlock safety net
        __builtin_amdgcn_s_sleep(1);
      }
      asm volatile("" ::: "memory");  // no hoisting data loads above poll
      // ---- stage h1_{u-1} (slot (u-1)&1) and h2_{u-2} (slot u&1) ----
      const f16* base1 =
          h1r + (size_t)((u - 1) & 1) * BH + (size_t)(row0 + sr) * HH + gq * 8;
      const f16* base2 =
          h2r + (size_t)(u & 1) * BH + (size_t)(row0 + sr) * HH + gq * 8;
      uint4 v[8];
      ld8_sc1(base1, base2, v);  // ends with vmcnt(4): h1 quads ready
      uint4* d1 = (uint4*)h1s;
      uint4* d2 = (uint4*)h2s;
#pragma unroll
      for (int q = 0; q < 4; ++q) {
        int gi = gq + q * 16;
        d1[sr * 64 + (gi ^ (sr & 7))] = v[q];
      }
      asm volatile("s_waitcnt vmcnt(0)" ::: "memory");  // h2 quads ready
#pragma unroll
      for (int q = 0; q < 4; ++q) {
        int gi = gq + q * 16;
        d2[sr * 64 + (gi ^ (sr & 7))] = v[4 + q];
      }
    }
    if (u < TT) {  // x -> swizzled LDS
      ((uint4*)xs)[sr * 16 + (gq ^ (sr & 7))] = xv;
    }
    __syncthreads();

    // ---- MFMA: wave (g,ch) -> 16 gate-cols, 32 rows, both layers ----
    f32x4 a0f0 = {0.f, 0.f, 0.f, 0.f}, a0f1 = {0.f, 0.f, 0.f, 0.f};
    f32x4 a1f0 = {0.f, 0.f, 0.f, 0.f}, a1f1 = {0.f, 0.f, 0.f, 0.f};
    if (u < TT) {  // L0 x-projection, K=128
#pragma unroll
      for (int kk = 0; kk < 4; ++kk) {
        f16x8 xA = ldfragx(xs, lm, kk * 4 + ls);
        f16x8 xB = ldfragx(xs, 16 + lm, kk * 4 + ls);
        a0f0 = __builtin_amdgcn_mfma_f32_16x16x32_f16(xA, wih0f[kk], a0f0, 0, 0, 0);
        a0f1 = __builtin_amdgcn_mfma_f32_16x16x32_f16(xB, wih0f[kk], a0f1, 0, 0, 0);
      }
    }
    if (u > 0) {  // h1_{u-1} feeds L0 recurrence AND L1 input projection
#pragma unroll
      for (int kk = 0; kk < 16; ++kk) {
        f16x8 hA = ldfragh(h1s, lm, kk * 4 + ls);
        f16x8 hB = ldfragh(h1s, 16 + lm, kk * 4 + ls);
        if (u < TT) {
          a0f0 = __builtin_amdgcn_mfma_f32_16x16x32_f16(hA, whh0f[kk], a0f0, 0, 0, 0);
          a0f1 = __builtin_amdgcn_mfma_f32_16x16x32_f16(hB, whh0f[kk], a0f1, 0, 0, 0);
        }
        a1f0 = __builtin_amdgcn_mfma_f32_16x16x32_f16(hA, wih1f[kk], a1f0, 0, 0, 0);
        a1f1 = __builtin_amdgcn_mfma_f32_16x16x32_f16(hB, wih1f[kk], a1f1, 0, 0, 0);
      }
      if (u >= 2) {  // L1 recurrence over h2_{u-2}
#pragma unroll
        for (int kk = 0; kk < 16; ++kk) {
          f16x8 hA = ldfragh(h2s, lm, kk * 4 + ls);
          f16x8 hB = ldfragh(h2s, 16 + lm, kk * 4 + ls);
          a1f0 = __builtin_amdgcn_mfma_f32_16x16x32_f16(hA, whh1f[kk], a1f0, 0, 0, 0);
          a1f1 = __builtin_amdgcn_mfma_f32_16x16x32_f16(hB, whh1f[kk], a1f1, 0, 0, 0);
        }
      }
    }
    // acc -> gs[layer][gl][row]; gl = g*32 + ch*16 + lm
    int gl = g * 32 + ch * 16 + lm;
    *(f32x4*)&gs[0][gl][ls * 4] = a0f0;
    *(f32x4*)&gs[0][gl][16 + ls * 4] = a0f1;
    *(f32x4*)&gs[1][gl][ls * 4] = a1f0;
    *(f32x4*)&gs[1][gl][16 + ls * 4] = a1f1;
    __syncthreads();

    // ---- elementwise LSTM cell: layer el, row er, cols eq*4..+3 ----
    bool act = el ? (u >= 1) : (u < TT);
    if (act) {
      int t_l = el ? (u - 1) : u;
      int slot = t_l & 1;
      union { uint64_t v; unsigned short us[4]; } pk;
#pragma unroll
      for (int j = 0; j < 4; ++j) {
        int cl = eq * 4 + j;
        float pi = gs[el][0 * 32 + cl][er] + bl[el][0][cl];
        float pf = gs[el][1 * 32 + cl][er] + bl[el][1][cl];
        float pg = gs[el][2 * 32 + cl][er] + bl[el][2][cl];
        float po = gs[el][3 * 32 + cl][er] + bl[el][3][cl];
        float ig = fsig(pi), fg = fsig(pf), gg = ftanh(pg), og = fsig(po);
        cst[j] = fg * cst[j] + ig * gg;
        pk.us[j] = __builtin_bit_cast(unsigned short, (f16)(og * ftanh(cst[j])));
      }
      uint64_t* dst = (uint64_t*)(ering + (size_t)slot * BH +
                                  (size_t)(row0 + er) * HH + col0 + eq * 4);
      st_agent_u64(dst, pk.v);
    }
    asm volatile("s_waitcnt vmcnt(0)" ::: "memory");  // h stores at MALL
    __syncthreads();                                  // all waves drained
    if (u < TT && tid == 0)  // parallel flag store: no RMW
      st_agent_u16(flags + ((size_t)grp * (TT + 1) + u) * 32 + slice, 1u);
  }
}

// ---------------- FC head: out[b] = h2_last[b][:] . fcw + fcb ----------------
__global__ __launch_bounds__(64) void k_fc(const f16* __restrict__ h2,
                                           const float* __restrict__ fcw,
                                           const float* __restrict__ fcb,
                                           float* __restrict__ out) {
  int b = blockIdx.x;
  int l = threadIdx.x;
  f16x8 hv = *(const f16x8*)(h2 + (size_t)b * HH + l * 8);
  float4 w0 = ((const float4*)fcw)[l * 2];
  float4 w1 = ((const float4*)fcw)[l * 2 + 1];
  float s = (float)hv[0] * w0.x + (float)hv[1] * w0.y + (float)hv[2] * w0.z +
            (float)hv[3] * w0.w + (float)hv[4] * w1.x + (float)hv[5] * w1.y +
            (float)hv[6] * w1.z + (float)hv[7] * w1.w;
#pragma unroll
  for (int off = 32; off > 0; off >>= 1) s += __shfl_down(s, off);
  if (l == 0) out[b] = s + fcb[0];
}

// ---------------- launch ----------------
extern "C" void kernel_launch(void* const* d_in, const int* in_sizes, int n_in,
                              void* d_out, int out_size, void* d_ws, size_t ws_size,
                              hipStream_t stream) {
  (void)in_sizes; (void)n_in; (void)out_size;

  const float* x    = (const float*)d_in[0];
  const float* wih0 = (const float*)d_in[1];
  const float* whh0 = (const float*)d_in[2];
  const float* bih0 = (const float*)d_in[3];
  const float* bhh0 = (const float*)d_in[4];
  const float* wih1 = (const float*)d_in[5];
  const float* whh1 = (const float*)d_in[6];
  const float* bih1 = (const float*)d_in[7];
  const float* bhh1 = (const float*)d_in[8];
  const float* fcw  = (const float*)d_in[9];
  const float* fcb  = (const float*)d_in[10];

  const size_t SZ_XT   = (size_t)TT * BB * II * 2;              // 16.8 MB
  const size_t SZ_WIH0 = (size_t)G4 * II * 2;
  const size_t SZ_W    = (size_t)G4 * HH * 2;
  const size_t SZ_B    = (size_t)G4 * 4;
  const size_t SZ_RING = (size_t)2 * BH * 2;
  const size_t SZ_FLG  = (size_t)NGRP * (TT + 1) * 64;          // 64B line per (grp,tick)
  const size_t TOTAL =
      SZ_XT + SZ_WIH0 + 3 * SZ_W + 2 * SZ_B + 2 * SZ_RING + SZ_FLG;

  if (ws_size < TOTAL) {
    k_diag<<<1, 1, 0, stream>>>((float*)d_out, (float)(ws_size >> 20));
    return;
  }

  char* ws = (char*)d_ws;
  size_t off = 0;
  f16* xt    = (f16*)(ws + off); off += SZ_XT;
  f16* cwih0 = (f16*)(ws + off); off += SZ_WIH0;
  f16* cwhh0 = (f16*)(ws + off); off += SZ_W;
  f16* cwih1 = (f16*)(ws + off); off += SZ_W;
  f16* cwhh1 = (f16*)(ws + off); off += SZ_W;
  float* b0  = (float*)(ws + off); off += SZ_B;
  float* b1  = (float*)(ws + off); off += SZ_B;
  f16* h1r   = (f16*)(ws + off); off += SZ_RING;
  f16* h2r   = (f16*)(ws + off); off += SZ_RING;
  uint16_t* flags = (uint16_t*)(ws + off); off += SZ_FLG;

  hipMemsetAsync(flags, 0, SZ_FLG, stream);
  k_conv_w<<<4096, 256, 0, stream>>>(wih0, whh0, wih1, whh1, bih0, bhh0, bih1, bhh1,
                                     cwih0, cwhh0, cwih1, cwhh1, b0, b1);
  k_conv_x<<<4096, 256, 0, stream>>>(x, xt);
  k_fused<<<128, 512, 0, stream>>>(xt, cwih0, cwhh0, cwih1, cwhh1, b0, b1,
                                   h1r, h2r, flags);
  // h2_255 is in ring slot (255&1)==1
  k_fc<<<256, 64, 0, stream>>>(h2r + BH, fcw, fcb, (float*)d_out);
}

// Round 9
// 1781.915 us; speedup vs baseline: 1.0473x; 1.0452x over previous
//
#include <hip/hip_runtime.h>
#include <stdint.h>

typedef _Float16 f16;
typedef _Float16 f16x8 __attribute__((ext_vector_type(8)));
typedef float f32x4 __attribute__((ext_vector_type(4)));

#define TT 256
#define BB 256
#define II 128
#define HH 512
#define G4 2048
#define NGRP 8
#define NSLC 16
static constexpr size_t BH = (size_t)BB * HH;

// ---------------- coherence helpers (sc1/agent ONLY — proven protocol) ----------------
__device__ __forceinline__ uint64_t ld_agent_u64(const uint64_t* p) {
  return __hip_atomic_load(p, __ATOMIC_RELAXED, __HIP_MEMORY_SCOPE_AGENT);
}
__device__ __forceinline__ void st_agent_u64(uint64_t* p, uint64_t v) {
  __hip_atomic_store(p, v, __ATOMIC_RELAXED, __HIP_MEMORY_SCOPE_AGENT);
}
__device__ __forceinline__ void st_agent_u16(uint16_t* p, uint16_t v) {
  __hip_atomic_store(p, v, __ATOMIC_RELAXED, __HIP_MEMORY_SCOPE_AGENT);
}
// 8x dwordx4 sc1 loads: 4 granule-groups of h1-row-part + 4 of h2-row-part.
// Ends with vmcnt(4) so the h1 quads are ready; caller drains vmcnt(0) before
// touching v[4..7]. All outputs early-clobber.
__device__ __forceinline__ void ld8_sc1(const void* b1, const void* b2, uint4 v[8]) {
  asm volatile(
      "global_load_dwordx4 %0, %8, off sc1\n\t"
      "global_load_dwordx4 %1, %8, off offset:256 sc1\n\t"
      "global_load_dwordx4 %2, %8, off offset:512 sc1\n\t"
      "global_load_dwordx4 %3, %8, off offset:768 sc1\n\t"
      "global_load_dwordx4 %4, %9, off sc1\n\t"
      "global_load_dwordx4 %5, %9, off offset:256 sc1\n\t"
      "global_load_dwordx4 %6, %9, off offset:512 sc1\n\t"
      "global_load_dwordx4 %7, %9, off offset:768 sc1\n\t"
      "s_waitcnt vmcnt(4)"
      : "=&v"(v[0]), "=&v"(v[1]), "=&v"(v[2]), "=&v"(v[3]),
        "=&v"(v[4]), "=&v"(v[5]), "=&v"(v[6]), "=&v"(v[7])
      : "v"(b1), "v"(b2)
      : "memory");
}

__device__ __forceinline__ float fsig(float x) {
  x = fminf(fmaxf(x, -30.f), 30.f);
  float e = __builtin_amdgcn_exp2f(-1.44269504f * x);
  return __builtin_amdgcn_rcpf(1.f + e);
}
__device__ __forceinline__ float ftanh(float x) {
  x = fminf(fmaxf(x, -15.f), 15.f);
  float e = __builtin_amdgcn_exp2f(-2.88539008f * x);  // exp(-2x)
  return (1.f - e) * __builtin_amdgcn_rcpf(1.f + e);
}

// swizzled LDS fragment reads (granule = 16B, XOR with row&7)
__device__ __forceinline__ f16x8 ldfragh(const f16* S, int row, int gi) {
  return *(const f16x8*)(S + row * 512 + ((gi ^ (row & 7)) * 8));
}
__device__ __forceinline__ f16x8 ldfragx(const f16* S, int row, int gi) {
  return *(const f16x8*)(S + row * 128 + ((gi ^ (row & 7)) * 8));
}

__global__ void k_diag(float* out, float val) { out[0] = val; }

// ---------------- x transpose/convert: [B][T][I] f32 -> [T][B][I] f16 ----------------
__global__ __launch_bounds__(256) void k_conv_x(const float* __restrict__ x,
                                                f16* __restrict__ xt) {
  int idx = blockIdx.x * 256 + threadIdx.x;  // unit = 8 floats
  int row = idx >> 4;                        // row = t*B + b
  int ii = (idx & 15) * 8;
  int t = row >> 8, b = row & 255;
  const float4* xs = (const float4*)(x + ((size_t)b * TT + t) * II + ii);
  float4 v0 = xs[0];
  float4 v1 = xs[1];
  f16x8 h;
  h[0] = (f16)v0.x; h[1] = (f16)v0.y; h[2] = (f16)v0.z; h[3] = (f16)v0.w;
  h[4] = (f16)v1.x; h[5] = (f16)v1.y; h[6] = (f16)v1.z; h[7] = (f16)v1.w;
  *(f16x8*)(xt + (size_t)row * II + ii) = h;
}

// ---------------- convert weights to f16, sum biases ----------------
__global__ __launch_bounds__(256) void k_conv_w(
    const float* __restrict__ wih0, const float* __restrict__ whh0,
    const float* __restrict__ wih1, const float* __restrict__ whh1,
    const float* __restrict__ bih0, const float* __restrict__ bhh0,
    const float* __restrict__ bih1, const float* __restrict__ bhh1,
    f16* owih0, f16* owhh0, f16* owih1, f16* owhh1, float* ob0, float* ob1) {
  int i = blockIdx.x * 256 + threadIdx.x;
  if (i < G4 * II) owih0[i] = (f16)wih0[i];
  if (i < G4 * HH) {
    owhh0[i] = (f16)whh0[i];
    owih1[i] = (f16)wih1[i];
    owhh1[i] = (f16)whh1[i];
  }
  if (i < G4) {
    ob0[i] = bih0[i] + bhh0[i];
    ob1[i] = bih1[i] + bhh1[i];
  }
}

// ---------------- fused 2-layer wavefront LSTM ----------------
// 128 blocks x 512 threads = 8 batch-groups (grp=bx&7, 32 rows) x 16
// col-slices (slice=bx>>3, 32 h-cols / 128 gate-cols). Tick u: L0 step u
// (u<T), L1 step u-1 (u>=1).
// WAVE ROLES (K-SPLIT): wave wid -> gate g = wid>>1, K-half kh = wid&1.
// Each wave computes ALL 32 block cols of its gate over K in
// [kh*256, kh*256+256) (x-proj: [kh*64, +64)). This halves per-wave LDS
// A-fragment reads (R8 bottleneck: 8 waves x 104 redundant ds_read_b128
// = 4.2us/tick); partials from the 2 K-halves are summed in the
// elementwise phase via the doubled gs buffer.
__global__ __launch_bounds__(512) void k_fused(
    const f16* __restrict__ xt,
    const f16* __restrict__ Wih0, const f16* __restrict__ Whh0,
    const f16* __restrict__ Wih1, const f16* __restrict__ Whh1,
    const float* __restrict__ b0, const float* __restrict__ b1,
    f16* __restrict__ h1r, f16* __restrict__ h2r, uint16_t* __restrict__ flags) {
  __shared__ __align__(16) f16 h1s[32 * 512];       // 32KB, swizzled
  __shared__ __align__(16) f16 h2s[32 * 512];       // 32KB, swizzled
  __shared__ __align__(16) f16 xs[32 * 128];        // 8KB, swizzled
  __shared__ __align__(16) float gs[2][128][2][37]; // 74KB partials [l][gcol][kh][row]
  __shared__ float bl[2][4][32];                    // 1KB bias

  int tid = threadIdx.x;
  int l64 = tid & 63;
  int wid = tid >> 6;        // 0..7
  int g = wid >> 1;          // gate (i,f,g,o)
  int kh = wid & 1;          // K-half
  int lm = l64 & 15, ls = l64 >> 4;
  int bx = blockIdx.x;
  int grp = bx & 7;
  int slice = bx >> 3;       // 0..15
  int col0 = slice * 32;
  int row0 = grp * 32;

  // ---- bias -> LDS ----
  if (tid < 256) {
    int el_ = tid >> 7, gt = (tid >> 5) & 3, cl = tid & 31;
    const float* bsrc = el_ ? b1 : b0;
    bl[el_][gt][cl] = bsrc[gt * HH + col0 + cl];
  }

  // ---- preload weight fragments: 52 f16x8 (live in unified VGPR/AGPR) ----
  // B-fragment (c,kk): W[g*512+col0+c*16+lm][kh*K/2 + kk*32 + ls*8 ..+8]
  f16x8 wi0[2][2], wh0[2][8], wi1[2][8], wh1[2][8];
#pragma unroll
  for (int c = 0; c < 2; ++c) {
    int wrow = g * 512 + col0 + c * 16 + lm;
#pragma unroll
    for (int kk = 0; kk < 8; ++kk) {
      size_t o = (size_t)wrow * HH + kh * 256 + kk * 32 + ls * 8;
      wh0[c][kk] = *(const f16x8*)(Whh0 + o);
      wi1[c][kk] = *(const f16x8*)(Wih1 + o);
      wh1[c][kk] = *(const f16x8*)(Whh1 + o);
    }
#pragma unroll
    for (int kk = 0; kk < 2; ++kk)
      wi0[c][kk] = *(const f16x8*)(Wih0 + (size_t)wrow * II + kh * 64 + kk * 32 + ls * 8);
  }

  // ---- elementwise role: 4 cells/thread ----
  int el = tid >> 8;         // layer
  int er = (tid >> 3) & 31;  // local batch row
  int eq = tid & 7;          // col quad (cols eq*4..+3 of 32)
  float cst[4] = {0.f, 0.f, 0.f, 0.f};
  f16* ering = el ? h2r : h1r;

  // staging role: row sr = tid>>4 (0..31), granule gq = tid&15 (16B units)
  int sr = tid >> 4;
  int gq = tid & 15;
  const uint64_t kTarget = 0x0001000100010001ULL;
  __syncthreads();

#pragma unroll 1
  for (int u = 0; u <= TT; ++u) {
    // prefetch x_u into regs (plain load; hides under poll)
    uint4 xv;
    if (u < TT)
      xv = ((const uint4*)(xt + ((size_t)u * BB + row0 + sr) * II))[gq];
    if (u > 0) {
      // poll the (grp, u-1) flag line: 16 u16 slots == 1 (2 u64 words)
      const uint64_t* fl =
          (const uint64_t*)(flags + ((size_t)grp * (TT + 1) + (u - 1)) * 32);
      int guard = 0;
      for (;;) {
        uint64_t v = ld_agent_u64(fl + (l64 & 1));
        if (__all(v == kTarget)) break;
        if (++guard > 500000) break;  // deadlock safety net
        __builtin_amdgcn_s_sleep(1);
      }
      asm volatile("" ::: "memory");  // no hoisting data loads above poll
      // ---- stage h1_{u-1} (slot (u-1)&1) and h2_{u-2} (slot u&1) ----
      const f16* base1 =
          h1r + (size_t)((u - 1) & 1) * BH + (size_t)(row0 + sr) * HH + gq * 8;
      const f16* base2 =
          h2r + (size_t)(u & 1) * BH + (size_t)(row0 + sr) * HH + gq * 8;
      uint4 v[8];
      ld8_sc1(base1, base2, v);  // ends with vmcnt(4): h1 quads ready
      uint4* d1 = (uint4*)h1s;
      uint4* d2 = (uint4*)h2s;
#pragma unroll
      for (int q = 0; q < 4; ++q) {
        int gi = gq + q * 16;
        d1[sr * 64 + (gi ^ (sr & 7))] = v[q];
      }
      asm volatile("s_waitcnt vmcnt(0)" ::: "memory");  // h2 quads ready
#pragma unroll
      for (int q = 0; q < 4; ++q) {
        int gi = gq + q * 16;
        d2[sr * 64 + (gi ^ (sr & 7))] = v[4 + q];
      }
    }
    if (u < TT) {  // x -> swizzled LDS
      ((uint4*)xs)[sr * 16 + (gq ^ (sr & 7))] = xv;
    }
    __syncthreads();

    // ---- MFMA: wave (g,kh) -> 32 gate-cols of gate g, K-half kh ----
    f32x4 a0[2][2] = {};  // [colfrag][rowfrag] layer0 partial
    f32x4 a1[2][2] = {};  // layer1 partial
    if (u < TT) {  // L0 x-projection, K-half = 64
#pragma unroll
      for (int kk = 0; kk < 2; ++kk) {
        int gi = kh * 8 + kk * 4 + ls;
        f16x8 xA = ldfragx(xs, lm, gi);
        f16x8 xB = ldfragx(xs, 16 + lm, gi);
#pragma unroll
        for (int c = 0; c < 2; ++c) {
          a0[c][0] = __builtin_amdgcn_mfma_f32_16x16x32_f16(xA, wi0[c][kk], a0[c][0], 0, 0, 0);
          a0[c][1] = __builtin_amdgcn_mfma_f32_16x16x32_f16(xB, wi0[c][kk], a0[c][1], 0, 0, 0);
        }
      }
    }
    if (u > 0) {  // h1_{u-1}: L0 recurrence + L1 input; h2_{u-2}: L1 recurrence
#pragma unroll
      for (int kk = 0; kk < 8; ++kk) {
        int gi = kh * 32 + kk * 4 + ls;
        f16x8 hA = ldfragh(h1s, lm, gi);
        f16x8 hB = ldfragh(h1s, 16 + lm, gi);
        if (u < TT) {
#pragma unroll
          for (int c = 0; c < 2; ++c) {
            a0[c][0] = __builtin_amdgcn_mfma_f32_16x16x32_f16(hA, wh0[c][kk], a0[c][0], 0, 0, 0);
            a0[c][1] = __builtin_amdgcn_mfma_f32_16x16x32_f16(hB, wh0[c][kk], a0[c][1], 0, 0, 0);
          }
        }
#pragma unroll
        for (int c = 0; c < 2; ++c) {
          a1[c][0] = __builtin_amdgcn_mfma_f32_16x16x32_f16(hA, wi1[c][kk], a1[c][0], 0, 0, 0);
          a1[c][1] = __builtin_amdgcn_mfma_f32_16x16x32_f16(hB, wi1[c][kk], a1[c][1], 0, 0, 0);
        }
        if (u >= 2) {
          f16x8 kA = ldfragh(h2s, lm, gi);
          f16x8 kB = ldfragh(h2s, 16 + lm, gi);
#pragma unroll
          for (int c = 0; c < 2; ++c) {
            a1[c][0] = __builtin_amdgcn_mfma_f32_16x16x32_f16(kA, wh1[c][kk], a1[c][0], 0, 0, 0);
            a1[c][1] = __builtin_amdgcn_mfma_f32_16x16x32_f16(kB, wh1[c][kk], a1[c][1], 0, 0, 0);
          }
        }
      }
    }
    // partials -> gs[layer][gcol][kh][row]; C layout: col=lane&15, row=ls*4+reg
#pragma unroll
    for (int c = 0; c < 2; ++c) {
      int gl = g * 32 + c * 16 + lm;
#pragma unroll
      for (int r = 0; r < 2; ++r) {
        *(f32x4*)&gs[0][gl][kh][r * 16 + ls * 4] = a0[c][r];
        *(f32x4*)&gs[1][gl][kh][r * 16 + ls * 4] = a1[c][r];
      }
    }
    __syncthreads();

    // ---- elementwise LSTM cell: layer el, row er, cols eq*4..+3 ----
    bool act = el ? (u >= 1) : (u < TT);
    if (act) {
      int t_l = el ? (u - 1) : u;
      int slot = t_l & 1;
      union { uint64_t v; unsigned short us[4]; } pk;
#pragma unroll
      for (int j = 0; j < 4; ++j) {
        int cl = eq * 4 + j;
        float pi = gs[el][0 * 32 + cl][0][er] + gs[el][0 * 32 + cl][1][er] + bl[el][0][cl];
        float pf = gs[el][1 * 32 + cl][0][er] + gs[el][1 * 32 + cl][1][er] + bl[el][1][cl];
        float pg = gs[el][2 * 32 + cl][0][er] + gs[el][2 * 32 + cl][1][er] + bl[el][2][cl];
        float po = gs[el][3 * 32 + cl][0][er] + gs[el][3 * 32 + cl][1][er] + bl[el][3][cl];
        float ig = fsig(pi), fg = fsig(pf), gg = ftanh(pg), og = fsig(po);
        cst[j] = fg * cst[j] + ig * gg;
        pk.us[j] = __builtin_bit_cast(unsigned short, (f16)(og * ftanh(cst[j])));
      }
      uint64_t* dst = (uint64_t*)(ering + (size_t)slot * BH +
                                  (size_t)(row0 + er) * HH + col0 + eq * 4);
      st_agent_u64(dst, pk.v);
    }
    asm volatile("s_waitcnt vmcnt(0)" ::: "memory");  // h stores at MALL
    __syncthreads();                                  // all waves drained
    if (u < TT && tid == 0)  // parallel flag store: no RMW
      st_agent_u16(flags + ((size_t)grp * (TT + 1) + u) * 32 + slice, 1u);
  }
}

// ---------------- FC head: out[b] = h2_last[b][:] . fcw + fcb ----------------
__global__ __launch_bounds__(64) void k_fc(const f16* __restrict__ h2,
                                           const float* __restrict__ fcw,
                                           const float* __restrict__ fcb,
                                           float* __restrict__ out) {
  int b = blockIdx.x;
  int l = threadIdx.x;
  f16x8 hv = *(const f16x8*)(h2 + (size_t)b * HH + l * 8);
  float4 w0 = ((const float4*)fcw)[l * 2];
  float4 w1 = ((const float4*)fcw)[l * 2 + 1];
  float s = (float)hv[0] * w0.x + (float)hv[1] * w0.y + (float)hv[2] * w0.z +
            (float)hv[3] * w0.w + (float)hv[4] * w1.x + (float)hv[5] * w1.y +
            (float)hv[6] * w1.z + (float)hv[7] * w1.w;
#pragma unroll
  for (int off = 32; off > 0; off >>= 1) s += __shfl_down(s, off);
  if (l == 0) out[b] = s + fcb[0];
}

// ---------------- launch ----------------
extern "C" void kernel_launch(void* const* d_in, const int* in_sizes, int n_in,
                              void* d_out, int out_size, void* d_ws, size_t ws_size,
                              hipStream_t stream) {
  (void)in_sizes; (void)n_in; (void)out_size;

  const float* x    = (const float*)d_in[0];
  const float* wih0 = (const float*)d_in[1];
  const float* whh0 = (const float*)d_in[2];
  const float* bih0 = (const float*)d_in[3];
  const float* bhh0 = (const float*)d_in[4];
  const float* wih1 = (const float*)d_in[5];
  const float* whh1 = (const float*)d_in[6];
  const float* bih1 = (const float*)d_in[7];
  const float* bhh1 = (const float*)d_in[8];
  const float* fcw  = (const float*)d_in[9];
  const float* fcb  = (const float*)d_in[10];

  const size_t SZ_XT   = (size_t)TT * BB * II * 2;              // 16.8 MB
  const size_t SZ_WIH0 = (size_t)G4 * II * 2;
  const size_t SZ_W    = (size_t)G4 * HH * 2;
  const size_t SZ_B    = (size_t)G4 * 4;
  const size_t SZ_RING = (size_t)2 * BH * 2;
  const size_t SZ_FLG  = (size_t)NGRP * (TT + 1) * 64;          // 64B line per (grp,tick)
  const size_t TOTAL =
      SZ_XT + SZ_WIH0 + 3 * SZ_W + 2 * SZ_B + 2 * SZ_RING + SZ_FLG;

  if (ws_size < TOTAL) {
    k_diag<<<1, 1, 0, stream>>>((float*)d_out, (float)(ws_size >> 20));
    return;
  }

  char* ws = (char*)d_ws;
  size_t off = 0;
  f16* xt    = (f16*)(ws + off); off += SZ_XT;
  f16* cwih0 = (f16*)(ws + off); off += SZ_WIH0;
  f16* cwhh0 = (f16*)(ws + off); off += SZ_W;
  f16* cwih1 = (f16*)(ws + off); off += SZ_W;
  f16* cwhh1 = (f16*)(ws + off); off += SZ_W;
  float* b0  = (float*)(ws + off); off += SZ_B;
  float* b1  = (float*)(ws + off); off += SZ_B;
  f16* h1r   = (f16*)(ws + off); off += SZ_RING;
  f16* h2r   = (f16*)(ws + off); off += SZ_RING;
  uint16_t* flags = (uint16_t*)(ws + off); off += SZ_FLG;

  hipMemsetAsync(flags, 0, SZ_FLG, stream);
  k_conv_w<<<4096, 256, 0, stream>>>(wih0, whh0, wih1, whh1, bih0, bhh0, bih1, bhh1,
                                     cwih0, cwhh0, cwih1, cwhh1, b0, b1);
  k_conv_x<<<4096, 256, 0, stream>>>(x, xt);
  k_fused<<<128, 512, 0, stream>>>(xt, cwih0, cwhh0, cwih1, cwhh1, b0, b1,
                                   h1r, h2r, flags);
  // h2_255 is in ring slot (255&1)==1
  k_fc<<<256, 64, 0, stream>>>(h2r + BH, fcw, fcb, (float*)d_out);
}